// Round 1
// 587.955 us; speedup vs baseline: 1.0170x; 1.0170x over previous
//
#include <hip/hip_runtime.h>
#include <hip/hip_bf16.h>

#define T_TOK 2048
#define H_DIM 2048
#define I_DIM 2048
#define E_NUM 8
#define TOPK  2

#define BM 128
#define BN 64
#define BK 64   // 8 granules of 16B (8 bf16) per LDS row
#define KT1 (H_DIM / BK)   // 32 K-tiles in gemm1
#define KT2 (I_DIM / BK)   // 32 K-tiles in gemm2

typedef float  floatx4 __attribute__((ext_vector_type(4)));
typedef __bf16 bf16x8  __attribute__((ext_vector_type(8)));
typedef __bf16 bf16x4  __attribute__((ext_vector_type(4)));

// XOR-swizzled LDS granule address (16B granules, 8 per 128-byte logical row).
__device__ __forceinline__ int swz(int row, int g) {
    return (row * 8 + (g ^ ((row >> 1) & 7))) * 16;
}

// Raw barrier that does NOT drain vmcnt: in-flight global prefetch loads
// survive across it (the whole point of the pipeline). ds_writes are drained
// explicitly; ds_reads completed via MFMA data-deps before we get here.
// sched_barrier(0) stops next-iter ds_reads hoisting above the s_barrier.
#define PIPE_BARRIER() do { \
    asm volatile("s_waitcnt lgkmcnt(0)" ::: "memory"); \
    __builtin_amdgcn_s_barrier(); \
    __builtin_amdgcn_sched_barrier(0); \
} while (0)

// ---------------------------------------------------------------------------
// Kernel 1: router — logits, top-2, renorm weights, per-expert lists,
//           PLUS fp32->bf16 conversion of hidden_states (it reads hs anyway).
// ---------------------------------------------------------------------------
__global__ __launch_bounds__(64) void router_kernel(
    const float* __restrict__ hs, const float* __restrict__ gate_w,
    int* __restrict__ counts, int* __restrict__ lists, float* __restrict__ wpair,
    __bf16* __restrict__ Xbf)
{
    const int t    = blockIdx.x;
    const int lane = threadIdx.x;

    float acc[E_NUM];
#pragma unroll
    for (int e = 0; e < E_NUM; e++) acc[e] = 0.f;

    const float4* hsrow = (const float4*)(hs + (size_t)t * H_DIM);
#pragma unroll
    for (int it = 0; it < (H_DIM / 4) / 64; it++) {
        const int c = lane + it * 64;
        const float4 x = hsrow[c];
        const bf16x4 v = {(__bf16)x.x, (__bf16)x.y, (__bf16)x.z, (__bf16)x.w};
        *(bf16x4*)(Xbf + (size_t)t * H_DIM + 4 * c) = v;
#pragma unroll
        for (int e = 0; e < E_NUM; e++) {
            const float4 w = ((const float4*)(gate_w + (size_t)e * H_DIM))[c];
            acc[e] += x.x * w.x + x.y * w.y + x.z * w.z + x.w * w.w;
        }
    }
#pragma unroll
    for (int e = 0; e < E_NUM; e++) {
        float v = acc[e];
        for (int off = 32; off >= 1; off >>= 1) v += __shfl_xor(v, off, 64);
        acc[e] = v;
    }
    if (lane == 0) {
        float l0 = -1e30f; int i0 = 0;
        for (int e = 0; e < E_NUM; e++) if (acc[e] > l0) { l0 = acc[e]; i0 = e; }
        float l1 = -1e30f; int i1 = (i0 == 0) ? 1 : 0;
        for (int e = 0; e < E_NUM; e++) if (e != i0 && acc[e] > l1) { l1 = acc[e]; i1 = e; }
        const float e1 = __expf(l1 - l0);
        const float s  = 1.f + e1;
        const int p0 = atomicAdd(&counts[i0], 1);
        lists[i0 * T_TOK + p0] = 2 * t;
        const int p1 = atomicAdd(&counts[i1], 1);
        lists[i1 * T_TOK + p1] = 2 * t + 1;
        wpair[2 * t]     = 1.f / s;
        wpair[2 * t + 1] = e1 / s;
    }
}

// ---------------------------------------------------------------------------
// Kernel 2: fused gate/up GEMM + SiLU.  A = silu(X@W1) * (X@W3), bf16 out.
// 128x64 tile, 4 waves. Software-pipelined: double-buffered LDS + 2-slot
// register prefetch; one raw barrier per K-iter; prefetch loads stay in
// flight across barriers (no vmcnt drain).
// ---------------------------------------------------------------------------
__global__ __launch_bounds__(256, 2) void gemm1_kernel(
    const __bf16* __restrict__ Xbf, const float* __restrict__ w1,
    const float* __restrict__ w3, const int* __restrict__ counts,
    const int* __restrict__ lists, __bf16* __restrict__ Abuf)
{
    const int e   = blockIdx.z;
    const int n_e = counts[e];
    const int m0  = blockIdx.y * BM;
    if (m0 >= n_e) return;
    const int n0 = blockIdx.x * BN;

    const int*   list = lists + e * T_TOK;
    const float* w1e  = w1 + (size_t)e * H_DIM * I_DIM;
    const float* w3e  = w3 + (size_t)e * H_DIM * I_DIM;

    __shared__ __align__(16) __bf16 Xs [2][BM * BK];   // 2 x 16 KB
    __shared__ __align__(16) __bf16 B1s[2][BN * BK];   // 2 x  8 KB
    __shared__ __align__(16) __bf16 B3s[2][BN * BK];   // 2 x  8 KB

    const int tid = threadIdx.x;
    const int xr8 = tid >> 3;        // 0..31
    const int xg  = tid & 7;         // 0..7
    const int kb  = tid >> 5;        // 0..7
    const int np  = tid & 31;        // 0..31

    int tok[4];
#pragma unroll
    for (int i = 0; i < 4; i++) {
        const int r = m0 + xr8 + 32 * i;
        tok[i] = (r < n_e) ? (list[r] >> 1) : 0;
    }

    const int wave = tid >> 6;
    const int lane = tid & 63;
    const int wm   = (wave >> 1) * 64;   // 0 or 64
    const int wn   = (wave & 1) * 32;    // 0 or 32
    const int lrow = lane & 15;
    const int quad = lane >> 4;

    floatx4 accG[4][2], accU[4][2];
#pragma unroll
    for (int i = 0; i < 4; i++)
#pragma unroll
        for (int j = 0; j < 2; j++) {
            accG[i][j] = (floatx4){0.f, 0.f, 0.f, 0.f};
            accU[i][j] = (floatx4){0.f, 0.f, 0.f, 0.f};
        }

    // Two register prefetch slots (A/B) -- all indices compile-time constant.
    bf16x8 xvA[4], xvB[4];
    float2 f1A[8], f1B[8], f3A[8], f3B[8];

#define G1_ISSUE(S, K0_) do { \
    const __bf16* xp_ = Xbf + (K0_) + 8 * xg; \
    _Pragma("unroll") \
    for (int i = 0; i < 4; i++) { \
        xv##S[i] = *(const bf16x8*)(xp_ + (size_t)tok[i] * H_DIM); \
    } \
    const float* s1_ = w1e + (size_t)((K0_) + 8 * kb) * I_DIM + n0 + 2 * np; \
    const float* s3_ = w3e + (size_t)((K0_) + 8 * kb) * I_DIM + n0 + 2 * np; \
    _Pragma("unroll") \
    for (int j = 0; j < 8; j++) { \
        f1##S[j] = *(const float2*)(s1_ + (size_t)j * I_DIM); \
        f3##S[j] = *(const float2*)(s3_ + (size_t)j * I_DIM); \
    } \
    __builtin_amdgcn_sched_barrier(0); \
} while (0)

#define G1_WRITE(S, BUF) do { \
    _Pragma("unroll") \
    for (int i = 0; i < 4; i++) { \
        *(bf16x8*)((char*)(Xs[BUF]) + swz(xr8 + 32 * i, xg)) = xv##S[i]; \
    } \
    bf16x8 wlo_, whi_; \
    _Pragma("unroll") \
    for (int j = 0; j < 8; j++) { wlo_[j] = (__bf16)f1##S[j].x; whi_[j] = (__bf16)f1##S[j].y; } \
    *(bf16x8*)((char*)(B1s[BUF]) + swz(2 * np,     kb)) = wlo_; \
    *(bf16x8*)((char*)(B1s[BUF]) + swz(2 * np + 1, kb)) = whi_; \
    _Pragma("unroll") \
    for (int j = 0; j < 8; j++) { wlo_[j] = (__bf16)f3##S[j].x; whi_[j] = (__bf16)f3##S[j].y; } \
    *(bf16x8*)((char*)(B3s[BUF]) + swz(2 * np,     kb)) = wlo_; \
    *(bf16x8*)((char*)(B3s[BUF]) + swz(2 * np + 1, kb)) = whi_; \
} while (0)

#define G1_COMPUTE(BUF) do { \
    _Pragma("unroll") \
    for (int s = 0; s < 2; s++) { \
        bf16x8 af_[4], b1f_[2], b3f_[2]; \
        _Pragma("unroll") \
        for (int i = 0; i < 4; i++) { \
            af_[i] = *(const bf16x8*)((char*)(Xs[BUF]) + swz(wm + i * 16 + lrow, 4 * s + quad)); \
        } \
        _Pragma("unroll") \
        for (int j = 0; j < 2; j++) { \
            b1f_[j] = *(const bf16x8*)((char*)(B1s[BUF]) + swz(wn + j * 16 + lrow, 4 * s + quad)); \
            b3f_[j] = *(const bf16x8*)((char*)(B3s[BUF]) + swz(wn + j * 16 + lrow, 4 * s + quad)); \
        } \
        _Pragma("unroll") \
        for (int i = 0; i < 4; i++) { \
            _Pragma("unroll") \
            for (int j = 0; j < 2; j++) { \
                accG[i][j] = __builtin_amdgcn_mfma_f32_16x16x32_bf16(af_[i], b1f_[j], accG[i][j], 0, 0, 0); \
                accU[i][j] = __builtin_amdgcn_mfma_f32_16x16x32_bf16(af_[i], b3f_[j], accU[i][j], 0, 0, 0); \
            } \
        } \
    } \
} while (0)

    // Pipeline: tile t's regs live in slot (t&1); iter t computes tile t-1
    // from LDS[(t-1)&1] and writes tile t to LDS[t&1].
    G1_ISSUE(A, 0);
    G1_ISSUE(B, BK);
    G1_WRITE(A, 0);
    PIPE_BARRIER();

#pragma unroll 1
    for (int t = 1; t < KT1 - 1; t += 2) {
        G1_ISSUE(A, (t + 1) * BK);       // tile t+1 -> slot A (free since t-1)
        G1_COMPUTE(0);                    // tile t-1
        G1_WRITE(B, 1);                   // tile t   (loaded 1 iter ago)
        PIPE_BARRIER();
        G1_ISSUE(B, (t + 2) * BK);       // tile t+2 -> slot B
        G1_COMPUTE(1);                    // tile t
        G1_WRITE(A, 0);                   // tile t+1
        PIPE_BARRIER();
    }
    // t = KT1-1 (31): no more prefetch
    G1_COMPUTE(0);                        // tile 30
    G1_WRITE(B, 1);                       // tile 31
    PIPE_BARRIER();
    G1_COMPUTE(1);                        // tile 31

#undef G1_ISSUE
#undef G1_WRITE
#undef G1_COMPUTE

    // epilogue: silu(g)*u -> Abuf[p]  (C/D layout: col=lane&15, row=quad*4+reg)
#pragma unroll
    for (int i = 0; i < 4; i++) {
#pragma unroll
        for (int r = 0; r < 4; r++) {
            const int row = m0 + wm + i * 16 + quad * 4 + r;
            if (row < n_e) {
                const int p = list[row];
                __bf16* dst = Abuf + (size_t)p * I_DIM + n0 + wn + lrow;
#pragma unroll
                for (int j = 0; j < 2; j++) {
                    const float g = accG[i][j][r];
                    const float u = accU[i][j][r];
                    const float sv = g / (1.f + __expf(-g));
                    dst[j * 16] = (__bf16)(sv * u);
                }
            }
        }
    }
}

// ---------------------------------------------------------------------------
// Kernel 3: down-proj GEMM.  Y[p] = A[p] @ W2[e], bf16 out.  Same pipeline.
// ---------------------------------------------------------------------------
__global__ __launch_bounds__(256, 3) void gemm2_kernel(
    const __bf16* __restrict__ Abuf, const float* __restrict__ w2,
    const int* __restrict__ counts, const int* __restrict__ lists,
    __bf16* __restrict__ Ybuf)
{
    const int e   = blockIdx.z;
    const int n_e = counts[e];
    const int m0  = blockIdx.y * BM;
    if (m0 >= n_e) return;
    const int n0 = blockIdx.x * BN;

    const int*   list = lists + e * T_TOK;
    const float* w2e  = w2 + (size_t)e * I_DIM * H_DIM;

    __shared__ __align__(16) __bf16 As[2][BM * BK];   // 2 x 16 KB
    __shared__ __align__(16) __bf16 Bs[2][BN * BK];   // 2 x  8 KB

    const int tid = threadIdx.x;
    const int ar8 = tid >> 3;        // 0..31
    const int ag  = tid & 7;         // 0..7
    const int kb  = tid >> 5;        // 0..7
    const int np  = tid & 31;        // 0..31

    int prow[4];
#pragma unroll
    for (int i = 0; i < 4; i++) {
        const int r = m0 + ar8 + 32 * i;
        prow[i] = (r < n_e) ? list[r] : 0;
    }

    const int wave = tid >> 6;
    const int lane = tid & 63;
    const int wm   = (wave >> 1) * 64;
    const int wn   = (wave & 1) * 32;
    const int lrow = lane & 15;
    const int quad = lane >> 4;

    floatx4 acc[4][2];
#pragma unroll
    for (int i = 0; i < 4; i++)
#pragma unroll
        for (int j = 0; j < 2; j++) acc[i][j] = (floatx4){0.f, 0.f, 0.f, 0.f};

    bf16x8 avA[4], avB[4];
    float2 f2A[8], f2B[8];

#define G2_ISSUE(S, K0_) do { \
    const __bf16* ap_ = Abuf + (K0_) + 8 * ag; \
    _Pragma("unroll") \
    for (int i = 0; i < 4; i++) { \
        av##S[i] = *(const bf16x8*)(ap_ + (size_t)prow[i] * I_DIM); \
    } \
    const float* s2_ = w2e + (size_t)((K0_) + 8 * kb) * H_DIM + n0 + 2 * np; \
    _Pragma("unroll") \
    for (int j = 0; j < 8; j++) { \
        f2##S[j] = *(const float2*)(s2_ + (size_t)j * H_DIM); \
    } \
    __builtin_amdgcn_sched_barrier(0); \
} while (0)

#define G2_WRITE(S, BUF) do { \
    _Pragma("unroll") \
    for (int i = 0; i < 4; i++) { \
        *(bf16x8*)((char*)(As[BUF]) + swz(ar8 + 32 * i, ag)) = av##S[i]; \
    } \
    bf16x8 wlo_, whi_; \
    _Pragma("unroll") \
    for (int j = 0; j < 8; j++) { wlo_[j] = (__bf16)f2##S[j].x; whi_[j] = (__bf16)f2##S[j].y; } \
    *(bf16x8*)((char*)(Bs[BUF]) + swz(2 * np,     kb)) = wlo_; \
    *(bf16x8*)((char*)(Bs[BUF]) + swz(2 * np + 1, kb)) = whi_; \
} while (0)

#define G2_COMPUTE(BUF) do { \
    _Pragma("unroll") \
    for (int s = 0; s < 2; s++) { \
        bf16x8 af_[4], bf_[2]; \
        _Pragma("unroll") \
        for (int i = 0; i < 4; i++) { \
            af_[i] = *(const bf16x8*)((char*)(As[BUF]) + swz(wm + i * 16 + lrow, 4 * s + quad)); \
        } \
        _Pragma("unroll") \
        for (int j = 0; j < 2; j++) { \
            bf_[j] = *(const bf16x8*)((char*)(Bs[BUF]) + swz(wn + j * 16 + lrow, 4 * s + quad)); \
        } \
        _Pragma("unroll") \
        for (int i = 0; i < 4; i++) { \
            _Pragma("unroll") \
            for (int j = 0; j < 2; j++) { \
                acc[i][j] = __builtin_amdgcn_mfma_f32_16x16x32_bf16(af_[i], bf_[j], acc[i][j], 0, 0, 0); \
            } \
        } \
    } \
} while (0)

    G2_ISSUE(A, 0);
    G2_ISSUE(B, BK);
    G2_WRITE(A, 0);
    PIPE_BARRIER();

#pragma unroll 1
    for (int t = 1; t < KT2 - 1; t += 2) {
        G2_ISSUE(A, (t + 1) * BK);
        G2_COMPUTE(0);
        G2_WRITE(B, 1);
        PIPE_BARRIER();
        G2_ISSUE(B, (t + 2) * BK);
        G2_COMPUTE(1);
        G2_WRITE(A, 0);
        PIPE_BARRIER();
    }
    G2_COMPUTE(0);
    G2_WRITE(B, 1);
    PIPE_BARRIER();
    G2_COMPUTE(1);

#undef G2_ISSUE
#undef G2_WRITE
#undef G2_COMPUTE

#pragma unroll
    for (int i = 0; i < 4; i++) {
#pragma unroll
        for (int r = 0; r < 4; r++) {
            const int row = m0 + wm + i * 16 + quad * 4 + r;
            if (row < n_e) {
                const int p = list[row];
                __bf16* dst = Ybuf + (size_t)p * H_DIM + n0 + wn + lrow;
#pragma unroll
                for (int j = 0; j < 2; j++) dst[j * 16] = (__bf16)acc[i][j][r];
            }
        }
    }
}

// ---------------------------------------------------------------------------
// Kernel 4: combine.  out[t] = w[2t]*Y[2t] + w[2t+1]*Y[2t+1]  (fp32 out)
// ---------------------------------------------------------------------------
__global__ __launch_bounds__(256) void combine_kernel(
    const __bf16* __restrict__ Ybuf, const float* __restrict__ wpair,
    float* __restrict__ out)
{
    const int idx = blockIdx.x * 256 + threadIdx.x;
    const int t   = idx >> 9;
    const int hc  = (idx & 511) * 4;
    const float w0 = wpair[2 * t];
    const float w1 = wpair[2 * t + 1];
    const __bf16* y0 = Ybuf + (size_t)(2 * t) * H_DIM + hc;
    const __bf16* y1 = y0 + H_DIM;
    float4 o;
    o.x = w0 * (float)y0[0] + w1 * (float)y1[0];
    o.y = w0 * (float)y0[1] + w1 * (float)y1[1];
    o.z = w0 * (float)y0[2] + w1 * (float)y1[2];
    o.w = w0 * (float)y0[3] + w1 * (float)y1[3];
    *(float4*)(out + (size_t)t * H_DIM + hc) = o;
}

// ---------------------------------------------------------------------------
extern "C" void kernel_launch(void* const* d_in, const int* in_sizes, int n_in,
                              void* d_out, int out_size, void* d_ws, size_t ws_size,
                              hipStream_t stream)
{
    const float* hs     = (const float*)d_in[0];
    const float* gate_w = (const float*)d_in[1];
    const float* w1     = (const float*)d_in[2];
    const float* w3     = (const float*)d_in[3];
    const float* w2     = (const float*)d_in[4];
    float*       out    = (float*)d_out;

    char* ws = (char*)d_ws;
    int*    counts = (int*)(ws + 0);
    float*  wpair  = (float*)(ws + 1024);
    int*    lists  = (int*)(ws + 32768);
    // Xbf (8 MB, live: router->gemm1) and Ybuf (16.8 MB, live: gemm2->combine)
    // share the same region — lifetimes don't overlap.
    __bf16* Xbf    = (__bf16*)(ws + (1 << 17));
    __bf16* Ybuf   = (__bf16*)(ws + (1 << 17));
    __bf16* Abuf   = (__bf16*)(ws + (1 << 17) +
                               (size_t)2 * T_TOK * H_DIM * sizeof(__bf16));

    hipMemsetAsync(counts, 0, E_NUM * sizeof(int), stream);

    router_kernel<<<T_TOK, 64, 0, stream>>>(hs, gate_w, counts, lists, wpair, Xbf);

    gemm1_kernel<<<dim3(I_DIM / BN, T_TOK / BM, E_NUM), 256, 0, stream>>>(
        Xbf, w1, w3, counts, lists, Abuf);

    gemm2_kernel<<<dim3(H_DIM / BN, T_TOK / BM, E_NUM), 256, 0, stream>>>(
        Abuf, w2, counts, lists, Ybuf);

    combine_kernel<<<(T_TOK * H_DIM / 4) / 256, 256, 0, stream>>>(Ybuf, wpair, out);
}